// Round 4
// baseline (1917.495 us; speedup 1.0000x reference)
//
#include <hip/hip_runtime.h>

// Problem constants
#define H 2048
#define W 2048
#define C 3
#define RAD 5
#define P (H + 2*RAD)           // 2058 padded state dimension
#define RS 2064                 // row stride (16-elem aligned)
#define PLANE ((size_t)P * RS)  // elements per channel plane
#define NITER 10

// Tile config
#define BX 64
#define BY 16
#define EX (BX + 2*RAD)         // 74
#define EY (BY + 2*RAD)         // 26
#define LSTR (EX + 1)           // 75

// ---------------------------------------------------------------------------
// Pad one channel: HWC float32 img -> padded f32 plane (edge replication)
// ---------------------------------------------------------------------------
__global__ void pad_kernel(const float* __restrict__ img, float* __restrict__ dst, int c) {
    int idx = blockIdx.x * blockDim.x + threadIdx.x;
    int total = P * P;
    if (idx >= total) return;
    int y = idx / P;
    int x = idx - y * P;
    int ys = min(max(y - RAD, 0), H - 1);
    int xs = min(max(x - RAD, 0), W - 1);
    dst[(size_t)y * RS + x] = img[((size_t)ys * W + xs) * C + c];
}

// ---------------------------------------------------------------------------
// One side-window iteration, BIT-EXACT emulation of the numpy f32 tap-loop:
//   d = 0; for ky in 0..10: for kx in 0..10: d += K[:,ky,kx] * x[ky:, kx:]
// Zero-weight taps are exact no-ops (+0), so only the support taps are folded,
// in row-major (ky,kx) order, each as round(w*u) then round(acc + p)
// (__fmul_rn/__fadd_rn — no FMA contraction, matching numpy's two roundings).
// Weights are the exact f32 values from the input kernel tensor.
// ---------------------------------------------------------------------------
__global__ __launch_bounds__(256)
void step_kernel(const float* __restrict__ src, float* __restrict__ dst,
                 const float* __restrict__ kern) {
    __shared__ float sU[EY][LSTR];

    // Exact f32 weights: kernel[0]=LL corner (w36 off-center, c36 center),
    // kernel[4]=Lk side (w66 off-center, c66 center).
    const float w36 = kern[0];               // [0,0,0,0]
    const float c36 = kern[5 * 11 + 5];      // [0,0,5,5]
    const float w66 = kern[4 * 121];         // [4,0,0,0]
    const float c66 = kern[4 * 121 + 5 * 11 + 5];

    const int x0 = blockIdx.x * BX;
    const int y0 = blockIdx.y * BY;
    const int tid = threadIdx.y * 64 + threadIdx.x;   // blockDim = (64,4)

    // Stage tile + halo; outside [0,P) is zero (conv zero padding)
    for (int i = tid; i < EY * EX; i += 256) {
        int r   = i / EX;
        int col = i - r * EX;
        int gy = y0 - RAD + r;
        int gx = x0 - RAD + col;
        float v = 0.0f;
        if (gy >= 0 && gy < P && gx >= 0 && gx < P)
            v = src[(size_t)gy * RS + gx];
        sU[r][col] = v;
    }
    __syncthreads();

    const int tx = threadIdx.x;
    const int gx = x0 + tx;
    const bool xok = (gx < P);

    #pragma unroll 1
    for (int rr = threadIdx.y; rr < BY; rr += 4) {
        int gy = y0 + rr;
        if (!xok || gy >= P) continue;

        float a0 = 0.f, a1 = 0.f, a2 = 0.f, a3 = 0.f;
        float a4 = 0.f, a5 = 0.f, a6 = 0.f, a7 = 0.f;

        #pragma unroll
        for (int ky = 0; ky < 11; ++ky) {
            #pragma unroll
            for (int kx = 0; kx < 11; ++kx) {
                const float uv = sU[rr + ky][tx + kx];
                const bool Lv = (ky <= 5), Rv = (ky >= 5);
                const bool Lh = (kx <= 5), Rh = (kx >= 5);
                const bool ctr = (ky == 5) && (kx == 5);
                const float wc = ctr ? c36 : w36;   // corner kernels
                const float ws = ctr ? c66 : w66;   // side kernels
                if (Lv && Lh) a0 = __fadd_rn(a0, __fmul_rn(wc, uv));  // LL
                if (Lv && Rh) a1 = __fadd_rn(a1, __fmul_rn(wc, uv));  // LR
                if (Rv && Lh) a2 = __fadd_rn(a2, __fmul_rn(wc, uv));  // RL
                if (Rv && Rh) a3 = __fadd_rn(a3, __fmul_rn(wc, uv));  // RR
                if (Lv)       a4 = __fadd_rn(a4, __fmul_rn(ws, uv));  // Lk
                if (Rv)       a5 = __fadd_rn(a5, __fmul_rn(ws, uv));  // Rk
                if (Lh)       a6 = __fadd_rn(a6, __fmul_rn(ws, uv));  // kL
                if (Rh)       a7 = __fadd_rn(a7, __fmul_rn(ws, uv));  // kR
            }
        }

        // argmin over |d|, first-index tie-break, order [LL,LR,RL,RR,Lk,Rk,kL,kR]
        float best = a0, ba = fabsf(a0);
        float t;
        t = fabsf(a1); if (t < ba) { ba = t; best = a1; }
        t = fabsf(a2); if (t < ba) { ba = t; best = a2; }
        t = fabsf(a3); if (t < ba) { ba = t; best = a3; }
        t = fabsf(a4); if (t < ba) { ba = t; best = a4; }
        t = fabsf(a5); if (t < ba) { ba = t; best = a5; }
        t = fabsf(a6); if (t < ba) { ba = t; best = a6; }
        t = fabsf(a7); if (t < ba) { ba = t; best = a7; }

        const float u = sU[rr + RAD][tx + RAD];
        dst[(size_t)gy * RS + gx] = __fadd_rn(u, best);
    }
}

// ---------------------------------------------------------------------------
// Crop interior of one f32 plane back into HWC float32 output
// ---------------------------------------------------------------------------
__global__ void crop_kernel(const float* __restrict__ src, float* __restrict__ dst, int c) {
    int idx = blockIdx.x * blockDim.x + threadIdx.x;
    int total = H * W;
    if (idx >= total) return;
    int y = idx / W;
    int x = idx - y * W;
    dst[((size_t)y * W + x) * C + c] = src[(size_t)(y + RAD) * RS + (x + RAD)];
}

extern "C" void kernel_launch(void* const* d_in, const int* in_sizes, int n_in,
                              void* d_out, int out_size, void* d_ws, size_t ws_size,
                              hipStream_t stream) {
    const float* img  = (const float*)d_in[0];
    const float* kern = (const float*)d_in[1];
    float* out = (float*)d_out;

    float* b0 = (float*)d_ws;
    float* b1 = b0 + PLANE;   // 2 planes * 2058*2064 * 4B = 34 MB

    dim3 sgrid((P + BX - 1) / BX, (P + BY - 1) / BY, 1);
    dim3 sblock(64, 4, 1);

    for (int c = 0; c < C; ++c) {
        {
            int total = P * P;
            pad_kernel<<<(total + 255) / 256, 256, 0, stream>>>(img, b0, c);
        }
        for (int i = 0; i < NITER; ++i) {
            const float* s = (i & 1) ? b1 : b0;
            float*       d = (i & 1) ? b0 : b1;
            step_kernel<<<sgrid, sblock, 0, stream>>>(s, d, kern);
        }
        {
            int total = H * W;
            crop_kernel<<<(total + 255) / 256, 256, 0, stream>>>(b0, out, c);
        }
    }
}